// Round 16
// baseline (921.958 us; speedup 1.0000x reference)
//
#include <hip/hip_runtime.h>
#include <stdint.h>

using f32x4 = __attribute__((ext_vector_type(4))) float;
using i32x4 = __attribute__((ext_vector_type(4))) int;

#define BK 64
#define BARRIER() __builtin_amdgcn_s_barrier()
#define SGB()     __builtin_amdgcn_sched_barrier(0)
#define SGB_NOMFMA() __builtin_amdgcn_sched_barrier(0x3F7)

__device__ __forceinline__ void gload_lds16(const void* g, void* l) {
    __builtin_amdgcn_global_load_lds(
        (const __attribute__((address_space(1))) unsigned int*)g,
        (__attribute__((address_space(3))) unsigned int*)l,
        16, 0, 0);
}

// ---------------------------------------------------------------------------
// Quant x: per-group-of-64 absmax int8. Outputs q (int8, EXACT) and
// dxT[g][M] f32 (transposed for coalesced GEMM panel staging).
// Quant math identical to rounds 1-15 (exact-f32, round-half-even).
// ---------------------------------------------------------------------------
__global__ void quant_kernel(const float* __restrict__ x,
                             int8_t* __restrict__ xq8,
                             float* __restrict__ dxT,
                             int total4, int kmask, int kshift, int M) {
    int idx = blockIdx.x * 256 + threadIdx.x;
    if (idx >= total4) return;
    f32x4 v = *(const f32x4*)(x + (size_t)idx * 4);
    float am = fmaxf(fmaxf(fabsf(v[0]), fabsf(v[1])),
                     fmaxf(fabsf(v[2]), fabsf(v[3])));
    am = fmaxf(am, __shfl_xor(am, 1));
    am = fmaxf(am, __shfl_xor(am, 2));
    am = fmaxf(am, __shfl_xor(am, 4));
    am = fmaxf(am, __shfl_xor(am, 8));
    float delta = fmaxf(am / 127.0f, 1e-5f);
    int pk = 0;
#pragma unroll
    for (int i = 0; i < 4; ++i) {
        float q = rintf(v[i] / delta);               // round-half-even
        q = fminf(fmaxf(q, -127.0f), 127.0f);
        pk |= ((int)q & 0xFF) << (8 * i);
    }
    *(int*)(xq8 + (size_t)idx * 4) = pk;
    if ((idx & 15) == 0) {                           // group leader
        size_t e0 = (size_t)idx * 4;
        int row = (int)(e0 >> kshift);
        int g   = ((int)e0 & kmask) >> 6;
        dxT[(size_t)g * M + row] = delta;
    }
}

// ---------------------------------------------------------------------------
// Quant W: per-row (n) absmax int8 + dw[n]. One block (256 thr) per row.
// (Reference keeps W fp32; int8 error ~0.4% rel, within absmax budget.)
// ---------------------------------------------------------------------------
__global__ void wquant_kernel(const float* __restrict__ W,
                              int8_t* __restrict__ qw8,
                              float* __restrict__ dw, int K) {
    const int n   = blockIdx.x;
    const int tid = threadIdx.x;
    const float* row = W + (size_t)n * K;
    f32x4 v[4];
    float am = 0.0f;
#pragma unroll
    for (int r = 0; r < 4; ++r) {
        v[r] = *(const f32x4*)(row + (size_t)(tid + r * 256) * 4);
#pragma unroll
        for (int i = 0; i < 4; ++i) am = fmaxf(am, fabsf(v[r][i]));
    }
#pragma unroll
    for (int o = 1; o < 64; o <<= 1) am = fmaxf(am, __shfl_xor(am, o));
    __shared__ float wm4[4];
    if ((tid & 63) == 0) wm4[tid >> 6] = am;
    __syncthreads();
    am = fmaxf(fmaxf(wm4[0], wm4[1]), fmaxf(wm4[2], wm4[3]));
    float dv = fmaxf(am / 127.0f, 1e-30f);
    if (tid == 0) dw[n] = dv;
    int8_t* qrow = qw8 + (size_t)n * K;
#pragma unroll
    for (int r = 0; r < 4; ++r) {
        int pk = 0;
#pragma unroll
        for (int i = 0; i < 4; ++i) {
            float q = rintf(v[r][i] / dv);
            q = fminf(fmaxf(q, -127.0f), 127.0f);
            pk |= ((int)q & 0xFF) << (8 * i);
        }
        *(int*)(qrow + (size_t)(tid + r * 256) * 4) = pk;
    }
}

// ---------------------------------------------------------------------------
// i8 GEMM 256x256, BK=64 (== quant group!). out[m][n] =
//   (sum_g dx[m][g] * S_g[m][n]) * dw[n] + bias[n],  S_g exact i32 MFMA.
// Round-13 schedule skeleton; per-stage call = 1 gload_lds16 (8KB half).
// LDS: 2 x {A 16K + B 16K} = 64K at 0; dx panel [NT=64][256] f32 = 64K at
// 65536 (staged once in prologue, never overwritten -> no WAR, no ledger).
// i8 tile rows = 64 B, 4 granules; swizzle p = c ^ ((row>>1)&3) spreads a
// 16-lane frag read over 8 distinct 16B slots (2-way on 32 banks = free).
// Both-sides rule #21: linear LDS dest, inverse-swizzled global source.
// vmcnt ledger (1 load/call; P1..P4 one stage each): invariant entering t =
// {(t-1).P2,(t-1).P3,(t-1).P4} = 3; +4 issued = 7; P4's vmcnt(3) retires 4
// (through t.P1) = everything tile t+1 reads (afL<-(t-1).P3, rot<-(t-1).P2,
// bfB<-(t-1).P4, afH<-t.P1, sx<-LDS panel). Prologue: 8 dx-calls + c1..c7;
// pre-loop vmcnt(3) proves dx+c1..c4; tile0.P4 vmcnt(3) retires c5,c6,c7,
// 0.P1 -> exact steady state. WAR proofs identical in form to r13 (each
// stage issues after a barrier that follows the dying region's
// lgkm-forced delivery). Rotation bfA pair + P4-end lgkm(0) as r13.
// ---------------------------------------------------------------------------
__global__ __launch_bounds__(512, 2) void gemm_kernel(
    const int8_t* __restrict__ A,    // [M][K] int8 (quantized x)
    const int8_t* __restrict__ B,    // [N][K] int8 (quantized W)
    const float* __restrict__ dxT,   // [K/64][M]
    const float* __restrict__ dw,    // [N]
    const float* __restrict__ bias,  // [N]
    float* __restrict__ out,         // [M][N] f32
    int M, int N, int K)
{
    __shared__ char lds[131072];     // 64K A/B dbuf + 64K dx panel

    const int tid  = threadIdx.x;
    const int lane = tid & 63;
    const int wv   = tid >> 6;
    const int wm   = wv >> 2;        // 0..1 (128 rows each)
    const int wn   = wv & 3;         // 0..3 (64 cols each)
    const int lr   = lane & 15;
    const int lk   = lane >> 4;      // 0..3 (k-chunk: k = lk*16 + 0..15)

    const int nbn = N / 256;
    const int nwg = gridDim.x;
    const int cpx = nwg >> 3;        // bijective XCD swizzle (nwg % 8 == 0)
    const int swz = (blockIdx.x & 7) * cpx + (blockIdx.x >> 3);
    const int bm0 = (swz / nbn) * 256;
    const int bn0 = (swz % nbn) * 256;

    const int8_t* Ag = A + (size_t)bm0 * K;
    const int8_t* Bg = B + (size_t)bn0 * K;
    const int NT = K / BK;           // 64

    // Staging offsets: granule u = tid (512 x 16B = one 8KB half-region).
    const int rho = tid >> 2;                       // local row 0..127
    const int cgr = (tid & 3) ^ ((rho >> 1) & 3);   // inverse swizzle on src
    const int offA = ((((rho >> 6) << 7) + (rho & 63))) * K + cgr * 16;
    const int offB = ((((rho >> 5) << 6) + (rho & 31))) * K + cgr * 16;
    const int ldsb = tid * 16;
    float* dxp = (float*)(lds + 65536);

#define STAGE_A(GSRC, DSTHALF) gload_lds16((GSRC) + offA, (DSTHALF) + ldsb)
#define STAGE_B(GSRC, DSTHALF) gload_lds16((GSRC) + offB, (DSTHALF) + ldsb)

    f32x4 acc[8][4] = {};

    // Prologue: dx panel (d1..d8: NT*256 f32 = 64KB), then c1..c7.
#pragma unroll
    for (int c = 0; c < 8; ++c) {
        int u = c * 512 + tid;
        gload_lds16(dxT + (size_t)(u >> 6) * M + bm0 + (u & 63) * 4,
                    dxp + (size_t)u * 4);
    }
    STAGE_A(Ag,               lds);                           // c1 A-h0(0)
    STAGE_B(Bg,               lds + 16384);                   // c2 B-h0(0)
    STAGE_B(Bg + 32 * K,      lds + 16384 + 8192);            // c3 B-h1(0)
    STAGE_A(Ag + 64 * K,      lds + 8192);                    // c4 A-h1(0)
    STAGE_A(Ag + BK,          lds + 32768);                   // c5 A-h0(1)
    STAGE_B(Bg + BK,          lds + 32768 + 16384);           // c6 B-h0(1)
    STAGE_B(Bg + BK + 32 * K, lds + 32768 + 16384 + 8192);    // c7 B-h1(1)
    asm volatile("s_waitcnt vmcnt(3)" ::: "memory");  // dx + c1..c4 proven
    SGB();
    BARRIER();

    // Fragment readers: one ds_read_b128 per frag (16 i8 along K per lane).
#define READ_AF(D, HALF)                                                       \
    { _Pragma("unroll") for (int m = 0; m < 4; ++m) {                          \
        int r_ = wm * 64 + m * 16 + lr;                                        \
        D[m] = *(const i32x4*)((HALF) + r_ * 64 + ((lk ^ ((r_ >> 1) & 3)) << 4)); } }
#define READ_BF(D, HALF)                                                       \
    { _Pragma("unroll") for (int n = 0; n < 2; ++n) {                          \
        int r_ = wn * 32 + n * 16 + lr;                                        \
        D[n] = *(const i32x4*)((HALF) + r_ * 64 + ((lk ^ ((r_ >> 1) & 3)) << 4)); } }

    // Swapped operands (bf first) -> transposed D: lane&15 = M-row,
    // (lane>>4)*4+j = N-col (r15-verified layout, shape-determined).
#define MQ(MO, NO, AF, BF, SO)                                                 \
    { _Pragma("unroll") for (int m = 0; m < 4; ++m)                            \
      _Pragma("unroll") for (int n = 0; n < 2; ++n) {                          \
        i32x4 d_ = __builtin_amdgcn_mfma_i32_16x16x64_i8(                      \
            BF[n], AF[m], (i32x4){0, 0, 0, 0}, 0, 0, 0);                       \
        _Pragma("unroll") for (int j = 0; j < 4; ++j)                          \
            acc[MO + m][NO + n][j] += sx_[SO + m] * (float)d_[j]; } }

    i32x4 bfA_e[2], bfA_o[2];
    READ_BF(bfA_e, lds + 16384);                     // rotation bfA(0)
    asm volatile("s_waitcnt lgkmcnt(0)" ::: "memory");
    SGB();
    BARRIER();                                       // plays B((t-1).P4)

#define TILE_ITER(T, CB, NB, BFA_IN, BFA_OUT)                                  \
    {                                                                          \
        char* cbA = lds + (CB);            char* cbB = cbA + 16384;            \
        char* nbA = lds + (NB);            char* nbB = nbA + 16384;            \
        const int8_t* AgT1 = Ag + (((T) + 1 < NT) ? (T) + 1 : NT - 1) * BK;    \
        const int8_t* AgT2 = Ag + (((T) + 2 < NT) ? (T) + 2 : NT - 1) * BK;    \
        const int8_t* BgT2 = Bg + (((T) + 2 < NT) ? (T) + 2 : NT - 1) * BK;    \
        i32x4 afL_[4], afH_[4], bfB_[2];                                       \
        float sx_[8];                                                          \
        /* P1: Q1 = afL x bfA ; sx loads ; stage A-h1(t+1)->nb */              \
        READ_AF(afL_, cbA);                                                    \
        { const float* q_ = dxp + (T) * 256 + wm * 128 + lr;                   \
          _Pragma("unroll") for (int m = 0; m < 8; ++m) sx_[m] = q_[m * 16]; } \
        STAGE_A(AgT1 + 64 * K, nbA + 8192);                                    \
        SGB(); BARRIER();                                                      \
        __builtin_amdgcn_s_setprio(1);                                         \
        MQ(0, 0, afL_, BFA_IN, 0);                                             \
        __builtin_amdgcn_s_setprio(0); SGB_NOMFMA();                           \
        /* P2: Q2 = afL x bfB ; stage B-h0(t+2)->cb */                         \
        READ_BF(bfB_, cbB + 8192);                                             \
        STAGE_B(BgT2, cbB);                                                    \
        SGB(); BARRIER();                                                      \
        __builtin_amdgcn_s_setprio(1);                                         \
        MQ(0, 2, afL_, bfB_, 0);                                               \
        __builtin_amdgcn_s_setprio(0); SGB_NOMFMA();                           \
        /* P3: Q3 = afH x bfA ; stage A-h0(t+2)->cb */                         \
        READ_AF(afH_, cbA + 8192);                                             \
        STAGE_A(AgT2, cbA);                                                    \
        SGB(); BARRIER();                                                      \
        __builtin_amdgcn_s_setprio(1);                                         \
        MQ(4, 0, afH_, BFA_IN, 4);                                             \
        __builtin_amdgcn_s_setprio(0); SGB_NOMFMA();                           \
        /* P4: stage B-h1(t+2)->cb ; vmcnt(3) ; rotation read ; Q4 */          \
        STAGE_B(BgT2 + 32 * K, cbB + 8192);                                    \
        asm volatile("s_waitcnt vmcnt(3)" ::: "memory");                       \
        SGB(); BARRIER();                                                      \
        READ_BF(BFA_OUT, nbB);                                                 \
        __builtin_amdgcn_s_setprio(1);                                         \
        MQ(4, 2, afH_, bfB_, 4);                                               \
        __builtin_amdgcn_s_setprio(0);                                         \
        asm volatile("s_waitcnt lgkmcnt(0)" ::: "memory");                     \
        SGB();                                                                 \
    }

    for (int tt = 0; tt < NT; tt += 2) {
        TILE_ITER(tt,     0,     32768, bfA_e, bfA_o);
        TILE_ITER(tt + 1, 32768, 0,     bfA_o, bfA_e);
    }
#undef TILE_ITER
#undef MQ
#undef READ_AF
#undef READ_BF
#undef STAGE_A
#undef STAGE_B

    asm volatile("s_waitcnt vmcnt(0) lgkmcnt(0)" ::: "memory"); // drain DMA
    BARRIER();

    // Epilogue (transposed D): row = r0 + mf*16 + lr; 4 consecutive N-cols
    // per lane -> f32x4 stores; dw folded here (g-invariant).
    const int r0   = bm0 + wm * 128;
    const int cC0  = bn0 + wn * 64;
    const int csub = lk << 2;
#pragma unroll
    for (int nf = 0; nf < 4; ++nf) {
        const int colbase = cC0 + nf * 16 + csub;
        const f32x4 dwv = *(const f32x4*)(dw + colbase);
        const f32x4 bv  = *(const f32x4*)(bias + colbase);
#pragma unroll
        for (int mf = 0; mf < 8; ++mf) {
            const int row = r0 + mf * 16 + lr;
            *(f32x4*)(out + (size_t)row * N + colbase) = acc[mf][nf] * dwv + bv;
        }
    }
}

extern "C" void kernel_launch(void* const* d_in, const int* in_sizes, int n_in,
                              void* d_out, int out_size, void* d_ws, size_t ws_size,
                              hipStream_t stream) {
    const float* x = (const float*)d_in[0];   // [M][K] f32
    const float* W = (const float*)d_in[1];   // [N][K] f32
    const float* b = (const float*)d_in[2];   // [N]   f32
    float* out = (float*)d_out;               // [M][N] f32

    const int N = in_sizes[2];                // 4096
    const int K = in_sizes[1] / N;            // 4096
    const int M = in_sizes[0] / K;            // 8192

    // ws: xq8 (M*K), qw8 (N*K), dxT (K/64*M f32), dw (N f32)  ~= 50 MB
    int8_t* xq8 = (int8_t*)d_ws;
    int8_t* qw8 = xq8 + (size_t)M * K;
    float*  dxT = (float*)(qw8 + (size_t)N * K);
    float*  dwv = dxT + (size_t)(K / 64) * M;

    int kshift = 0; while ((1 << kshift) < K) ++kshift;   // K = 2^kshift
    const int t4x = (int)(((long long)M * K) / 4);
    quant_kernel<<<(t4x + 255) / 256, 256, 0, stream>>>(
        x, xq8, dxT, t4x, K - 1, kshift, M);
    wquant_kernel<<<N, 256, 0, stream>>>(W, qw8, dwv, K);

    dim3 grid((M / 256) * (N / 256));         // 512 blocks
    gemm_kernel<<<grid, 512, 0, stream>>>(xq8, qw8, dxT, dwv, b, out, M, N, K);
}

// Round 17
// 262.763 us; speedup vs baseline: 3.5087x; 3.5087x over previous
//
#include <hip/hip_runtime.h>

using f32x4  = __attribute__((ext_vector_type(4))) float;
using bf16x8 = __attribute__((ext_vector_type(8))) __bf16;
using u16x4  = __attribute__((ext_vector_type(4))) unsigned short;

#define BK 64
#define REG_HALF   8192      // ushorts: 128 rows x 64 cols
#define A_OFS      0
#define B_OFS      16384
#define BUF_STRIDE 32768     // one buffer = A(32KB)+B(32KB) = 64 KB

#define BARRIER() __builtin_amdgcn_s_barrier()
#define SGB()     __builtin_amdgcn_sched_barrier(0)
#define SGB_NOMFMA() __builtin_amdgcn_sched_barrier(0x3F7)

__device__ __forceinline__ unsigned short f32_to_bf16_bits(float f) {
    unsigned int u = __builtin_bit_cast(unsigned int, f);
    u = (u + 0x7fffu + ((u >> 16) & 1u)) >> 16;
    return (unsigned short)u;
}

__device__ __forceinline__ void gload_lds16(const void* g, void* l) {
    __builtin_amdgcn_global_load_lds(
        (const __attribute__((address_space(1))) unsigned int*)g,
        (__attribute__((address_space(3))) unsigned int*)l,
        16, 0, 0);
}

// ---------------------------------------------------------------------------
// Fused prep: fake-quant x (exact-f32 math, bf16 store) + W f32->bf16.
// ---------------------------------------------------------------------------
__global__ void prep_kernel(const float* __restrict__ x,
                            const float* __restrict__ W,
                            unsigned short* __restrict__ xq,
                            unsigned short* __restrict__ Wb,
                            int t4x, int t4w) {
    int idx = blockIdx.x * 256 + threadIdx.x;
    if (idx < t4x) {
        f32x4 v = *(const f32x4*)(x + (size_t)idx * 4);
        float am = fmaxf(fmaxf(fabsf(v[0]), fabsf(v[1])),
                         fmaxf(fabsf(v[2]), fabsf(v[3])));
        am = fmaxf(am, __shfl_xor(am, 1));
        am = fmaxf(am, __shfl_xor(am, 2));
        am = fmaxf(am, __shfl_xor(am, 4));
        am = fmaxf(am, __shfl_xor(am, 8));
        float delta = fmaxf(am / 127.0f, 1e-5f);
        u16x4 o;
#pragma unroll
        for (int i = 0; i < 4; ++i) {
            float q = rintf(v[i] / delta);           // round-half-even
            q = fminf(fmaxf(q, -127.0f), 127.0f);
            o[i] = f32_to_bf16_bits(q * delta);
        }
        *(u16x4*)(xq + (size_t)idx * 4) = o;
    } else {
        int j = idx - t4x;
        if (j < t4w) {
            f32x4 v = *(const f32x4*)(W + (size_t)j * 4);
            u16x4 o;
#pragma unroll
            for (int i = 0; i < 4; ++i) o[i] = f32_to_bf16_bits(v[i]);
            *(u16x4*)(Wb + (size_t)j * 4) = o;
        }
    }
}

// Fragment readers (region base pointer; T2-swizzled column) ---------------
__device__ __forceinline__ void read_af(bf16x8 (&dst)[4][2],
    const unsigned short* reg, int wm, int lr, int lk, int sx) {
#pragma unroll
    for (int m = 0; m < 4; ++m)
#pragma unroll
        for (int kk = 0; kk < 2; ++kk)
            dst[m][kk] = *(const bf16x8*)(reg
                + (wm * 64 + m * 16 + lr) * 64 + ((((kk << 2) + lk) ^ sx) << 3));
}

__device__ __forceinline__ void read_bf(bf16x8 (&dst)[2][2],
    const unsigned short* reg, int wn, int lr, int lk, int sx) {
#pragma unroll
    for (int n = 0; n < 2; ++n)
#pragma unroll
        for (int kk = 0; kk < 2; ++kk)
            dst[n][kk] = *(const bf16x8*)(reg
                + (wn * 32 + n * 16 + lr) * 64 + ((((kk << 2) + lk) ^ sx) << 3));
}

// Operand-SWAPPED quad: mfma(bf, af) -> D-fragment transposed:
// lane&15 = M-row within m-frag, (lane>>4)*4+j = N-col within n-frag.
// Same products, same f32 accumulation datapath -> numerically identical.
__device__ __forceinline__ void mfma_quad(f32x4 (&acc)[8][4], int mo, int no,
    const bf16x8 (&af)[4][2], const bf16x8 (&bf)[2][2]) {
#pragma unroll
    for (int m = 0; m < 4; ++m)
#pragma unroll
        for (int n = 0; n < 2; ++n)
#pragma unroll
            for (int kk = 0; kk < 2; ++kk)
                acc[mo + m][no + n] = __builtin_amdgcn_mfma_f32_16x16x32_bf16(
                    bf[n][kk], af[m][kk], acc[mo + m][no + n], 0, 0, 0);
}

// ---------------------------------------------------------------------------
// 256x256 bf16 GEMM (B^T). Converged structure (rounds 10-15):
// 4 phases/tile, one vmcnt(6)/tile, rotation bfA pair, stage stream
// P1:A-h1(t+1)->nb, P2:B-h0(t+2)->cb, P3:A-h0(t+2)->cb, P4:B-h1(t+2)->cb.
// Phase = { reads_p ; stage_p ; SGB ; BARRIER ; setprio1 16xMFMA setprio0 ;
//           SGB_NOMFMA }, P4 adds the single vmcnt(6) before its barrier
// and the rotation read + lgkmcnt(0) after it.
// vmcnt(6) counting: leaves exactly {tP2,tP3,tP4} outstanding -> retires
// through t.P1 = everything tile t+1 reads. WAR: every stage follows a
// barrier that follows the dying region's consuming MFMA (lgkm-delivered).
// Operand-swapped MFMA -> transposed D -> epilogue is 32 dwordx4 stores
// per thread (16 rows x 64B contiguous per wave-store), dwordx4 bias loads.
// Register budget: acc 128 AGPR (MFMA C chain) + ~110 VGPR frags — at the
// 128-VGPR wall; deeper rotation/pipelining spills (r5/r9/r11/r16 evidence).
// ---------------------------------------------------------------------------
__global__ __launch_bounds__(512, 2) void gemm_kernel(
    const unsigned short* __restrict__ A,   // [M][K] bf16 bits (quantized x)
    const unsigned short* __restrict__ B,   // [N][K] bf16 bits (W)
    const float* __restrict__ bias,         // [N]
    float* __restrict__ out,                // [M][N] f32
    int M, int N, int K)
{
    __shared__ unsigned short lds[2 * BUF_STRIDE];   // 128 KiB

    const int tid  = threadIdx.x;
    const int lane = tid & 63;
    const int wv   = tid >> 6;
    const int wm   = wv >> 2;        // 0..1  (128 rows each)
    const int wn   = wv & 3;         // 0..3  (64 cols each)
    const int lr   = lane & 15;
    const int lk   = lane >> 4;      // 0..3
    const int sx   = lr & 7;

    const int nbn = N / 256;
    const int nwg = gridDim.x;
    const int cpx = nwg >> 3;        // bijective XCD swizzle (nwg % 8 == 0)
    const int swz = (blockIdx.x & 7) * cpx + (blockIdx.x >> 3);
    const int bm0 = (swz / nbn) * 256;
    const int bn0 = (swz % nbn) * 256;

    const unsigned short* Ag = A + (size_t)bm0 * K;
    const unsigned short* Bg = B + (size_t)bn0 * K;
    const int NT = K / BK;           // 64, even

    // Hoisted per-lane staging offsets (element units, 32-bit safe).
    const int gr0 = tid >> 3,         gr1 = (512 + tid) >> 3;
    const int c0  = ((tid & 7) ^ (gr0 & 7)) << 3;
    const int c1  = ((tid & 7) ^ (gr1 & 7)) << 3;
    const int offA0 = ((((gr0 >> 6) << 7) + (gr0 & 63))) * K + c0;
    const int offA1 = ((((gr1 >> 6) << 7) + (gr1 & 63))) * K + c1;
    const int offB0 = ((((gr0 >> 5) << 6) + (gr0 & 31))) * K + c0;
    const int offB1 = ((((gr1 >> 5) << 6) + (gr1 & 31))) * K + c1;
    const int ldsu0 = tid * 8, ldsu1 = (512 + tid) * 8;

#define STAGE_AH0(TK, DST) { gload_lds16(Ag + offA0 + (TK), (DST) + ldsu0); \
                             gload_lds16(Ag + offA1 + (TK), (DST) + ldsu1); }
#define STAGE_AH1(TK, DST) { gload_lds16(Ag + offA0 + 64*K + (TK), (DST) + ldsu0); \
                             gload_lds16(Ag + offA1 + 64*K + (TK), (DST) + ldsu1); }
#define STAGE_BH0(TK, DST) { gload_lds16(Bg + offB0 + (TK), (DST) + ldsu0); \
                             gload_lds16(Bg + offB1 + (TK), (DST) + ldsu1); }
#define STAGE_BH1(TK, DST) { gload_lds16(Bg + offB0 + 32*K + (TK), (DST) + ldsu0); \
                             gload_lds16(Bg + offB1 + 32*K + (TK), (DST) + ldsu1); }

    f32x4 acc[8][4] = {};

    // Prologue, ledger call order c1..c7 (oldest first):
    STAGE_AH0(0,  lds + A_OFS);                          // c1 A-h0(0)
    STAGE_BH0(0,  lds + B_OFS);                          // c2 B-h0(0)
    STAGE_BH1(0,  lds + B_OFS + REG_HALF);               // c3 B-h1(0)
    STAGE_AH1(0,  lds + A_OFS + REG_HALF);               // c4 A-h1(0)
    STAGE_AH0(BK, lds + BUF_STRIDE + A_OFS);             // c5 A-h0(1)
    STAGE_BH0(BK, lds + BUF_STRIDE + B_OFS);             // c6 B-h0(1)
    STAGE_BH1(BK, lds + BUF_STRIDE + B_OFS + REG_HALF);  // c7 B-h1(1)
    asm volatile("s_waitcnt vmcnt(6)" ::: "memory");     // c1..c4 proven
    SGB();
    BARRIER();

    bf16x8 bfA_e[2][2], bfA_o[2][2];
    read_bf(bfA_e, lds + B_OFS, wn, lr, lk, sx);         // rotation bfA(0)
    asm volatile("s_waitcnt lgkmcnt(0)" ::: "memory");   // delivered
    SGB();
    BARRIER();                                           // plays B((t-1).P4)

#define TILE_ITER(T, CB, NB, BFA_IN, BFA_OUT)                                  \
    {                                                                          \
        unsigned short* cb_ = (CB);                                            \
        unsigned short* nb_ = (NB);                                            \
        const int tk1 = (((T) + 1 < NT) ? (T) + 1 : NT - 1) * BK;              \
        const int tk2 = (((T) + 2 < NT) ? (T) + 2 : NT - 1) * BK;              \
        bf16x8 afL_[4][2], afH_[4][2], bfB_[2][2];                             \
        /* P1: Q1 = afL x bfA_in */                                            \
        read_af(afL_, cb_ + A_OFS, wm, lr, lk, sx);                            \
        STAGE_AH1(tk1, nb_ + A_OFS + REG_HALF);                                \
        SGB(); BARRIER();                                                      \
        __builtin_amdgcn_s_setprio(1);                                         \
        mfma_quad(acc, 0, 0, afL_, BFA_IN);                                    \
        __builtin_amdgcn_s_setprio(0); SGB_NOMFMA();                           \
        /* P2: Q2 = afL x bfB */                                               \
        read_bf(bfB_, cb_ + B_OFS + REG_HALF, wn, lr, lk, sx);                 \
        STAGE_BH0(tk2, cb_ + B_OFS);                                           \
        SGB(); BARRIER();                                                      \
        __builtin_amdgcn_s_setprio(1);                                         \
        mfma_quad(acc, 0, 2, afL_, bfB_);                                      \
        __builtin_amdgcn_s_setprio(0); SGB_NOMFMA();                           \
        /* P3: Q3 = afH x bfA_in */                                            \
        read_af(afH_, cb_ + A_OFS + REG_HALF, wm, lr, lk, sx);                 \
        STAGE_AH0(tk2, cb_ + A_OFS);                                           \
        SGB(); BARRIER();                                                      \
        __builtin_amdgcn_s_setprio(1);                                         \
        mfma_quad(acc, 4, 0, afH_, BFA_IN);                                    \
        __builtin_amdgcn_s_setprio(0); SGB_NOMFMA();                           \
        /* P4: single tile wait; rotation read after its proof barrier */      \
        STAGE_BH1(tk2, cb_ + B_OFS + REG_HALF);                                \
        asm volatile("s_waitcnt vmcnt(6)" ::: "memory");                       \
        SGB(); BARRIER();                                                      \
        read_bf(BFA_OUT, nb_ + B_OFS, wn, lr, lk, sx);                         \
        __builtin_amdgcn_s_setprio(1);                                         \
        mfma_quad(acc, 4, 2, afH_, bfB_);                                      \
        __builtin_amdgcn_s_setprio(0);                                         \
        asm volatile("s_waitcnt lgkmcnt(0)" ::: "memory");                     \
        SGB();                                                                 \
    }

    for (int tt = 0; tt < NT; tt += 2) {
        TILE_ITER(tt,     lds,              lds + BUF_STRIDE, bfA_e, bfA_o);
        TILE_ITER(tt + 1, lds + BUF_STRIDE, lds,              bfA_o, bfA_e);
    }
#undef TILE_ITER
#undef STAGE_AH0
#undef STAGE_AH1
#undef STAGE_BH0
#undef STAGE_BH1

    asm volatile("s_waitcnt vmcnt(0) lgkmcnt(0)" ::: "memory"); // drain DMA
    BARRIER();

    // Epilogue (transposed D-fragment): lane&15 = M-row, (lane>>4)*4+j =
    // N-col. Each acc[mf][nf] is 4 consecutive N-cols at one row ->
    // float4 store. Wave-store = 16 rows x 64 B contiguous.
    const int r0   = bm0 + wm * 128;          // + mf*16 + lr
    const int cC0  = bn0 + wn * 64;           // + nf*16 + (lk<<2)
    const int csub = lk << 2;
#pragma unroll
    for (int nf = 0; nf < 4; ++nf) {
        const int colbase = cC0 + nf * 16 + csub;
        const f32x4 bv = *(const f32x4*)(bias + colbase);
#pragma unroll
        for (int mf = 0; mf < 8; ++mf) {
            const int row = r0 + mf * 16 + lr;
            *(f32x4*)(out + (size_t)row * N + colbase) = acc[mf][nf] + bv;
        }
    }
}

extern "C" void kernel_launch(void* const* d_in, const int* in_sizes, int n_in,
                              void* d_out, int out_size, void* d_ws, size_t ws_size,
                              hipStream_t stream) {
    const float* x = (const float*)d_in[0];   // [M][K] f32
    const float* W = (const float*)d_in[1];   // [N][K] f32
    const float* b = (const float*)d_in[2];   // [N]   f32
    float* out = (float*)d_out;               // [M][N] f32

    const int N = in_sizes[2];                // 4096
    const int K = in_sizes[1] / N;            // 4096
    const int M = in_sizes[0] / K;            // 8192

    unsigned short* xq = (unsigned short*)d_ws;            // 64 MB
    unsigned short* Wb = xq + (size_t)M * K;               // 32 MB

    const int t4x = (int)(((long long)M * K) / 4);
    const int t4w = (int)(((long long)N * K) / 4);
    prep_kernel<<<(t4x + t4w + 255) / 256, 256, 0, stream>>>(x, W, xq, Wb, t4x, t4w);

    dim3 grid((M / 256) * (N / 256));         // 512 blocks
    gemm_kernel<<<grid, 512, 0, stream>>>(xq, Wb, b, out, M, N, K);
}